// Round 7
// baseline (174.620 us; speedup 1.0000x reference)
//
#include <hip/hip_runtime.h>
#include <hip/hip_bf16.h>
#include <stdint.h>

#define B_ 32
#define S_ 512
#define D_ 768
#define O_ 768
#define E_ 8
#define YSIZE (B_ * S_ * O_)   // 12582912
#define BK 32
#define WSLICE (O_ * D_)       // 589824 elements per expert slice

typedef __attribute__((ext_vector_type(8))) short bf16x8;
typedef __attribute__((ext_vector_type(4))) float f32x4;

static __device__ __forceinline__ unsigned short f2bf(float f) {
  union { float f; uint32_t u; } v; v.f = f;
  uint32_t u = v.u;
  uint32_t r = u + 0x7fff + ((u >> 16) & 1);   // RNE
  return (unsigned short)(r >> 16);
}

static __device__ __forceinline__ uint32_t cvt_pk_bf16(float lo, float hi) {
  uint32_t r;
  asm("v_cvt_pk_bf16_f32 %0, %1, %2" : "=v"(r) : "v"(lo), "v"(hi));
  return r;   // [hi_bf16 | lo_bf16], RNE — bit-identical to f2bf pair
}

static __device__ __forceinline__ void async_load16(const void* g, void* l) {
  __builtin_amdgcn_global_load_lds(
      (const __attribute__((address_space(1))) void*)g,
      (__attribute__((address_space(3))) void*)l, 16, 0, 0);
}

// ---------------- Kernel 1: pool partial sums + x -> bf16 ----------------
__global__ __launch_bounds__(192) void k_pool_convert(
    const float* __restrict__ x, unsigned short* __restrict__ xb,
    float* __restrict__ psum) {
  int t  = threadIdx.x;          // 0..191
  int b  = blockIdx.x;
  int sc = blockIdx.y;           // 0..15, 32 s-rows each
  size_t rowbase = (size_t)(b * S_ + sc * 32) * D_;
  const float* xp = x + rowbase + 4 * t;
  unsigned short* op = xb + rowbase + 4 * t;
  float4 sum = {0.f, 0.f, 0.f, 0.f};
  #pragma unroll 8
  for (int s = 0; s < 32; ++s) {
    float4 v = *(const float4*)(xp + (size_t)s * D_);
    sum.x += v.x; sum.y += v.y; sum.z += v.z; sum.w += v.w;
    ushort4 o;
    o.x = f2bf(v.x); o.y = f2bf(v.y); o.z = f2bf(v.z); o.w = f2bf(v.w);
    *(ushort4*)(op + (size_t)s * D_) = o;
  }
  *(float4*)(psum + (size_t)(b * 16 + sc) * D_ + 4 * t) = sum;
}

// ---------------- Kernel 2: logits + top-2 + softmax (one block per b) ----
__global__ __launch_bounds__(256) void k_logits(
    const float* __restrict__ psum, const float* __restrict__ w_gate,
    int* __restrict__ eidx, float* __restrict__ gval) {
  int b = blockIdx.x;
  int tid = threadIdx.x;
  float acc[E_];
  #pragma unroll
  for (int e = 0; e < E_; ++e) acc[e] = 0.f;

  for (int d = tid; d < D_; d += 256) {
    float p = 0.f;
    #pragma unroll
    for (int c = 0; c < 16; ++c) p += psum[(size_t)(b * 16 + c) * D_ + d];
    p *= (1.0f / (float)S_);
    const float* wg = w_gate + d * E_;
    #pragma unroll
    for (int e = 0; e < E_; ++e) acc[e] += p * wg[e];
  }
  #pragma unroll
  for (int off = 32; off > 0; off >>= 1) {
    #pragma unroll
    for (int e = 0; e < E_; ++e) acc[e] += __shfl_down(acc[e], off, 64);
  }
  __shared__ float part[4][E_];
  if ((tid & 63) == 0) {
    #pragma unroll
    for (int e = 0; e < E_; ++e) part[tid >> 6][e] = acc[e];
  }
  __syncthreads();
  if (tid == 0) {
    float lg[E_];
    #pragma unroll
    for (int e = 0; e < E_; ++e)
      lg[e] = part[0][e] + part[1][e] + part[2][e] + part[3][e];
    int i0 = 0; float v0 = lg[0];
    #pragma unroll
    for (int e = 1; e < E_; ++e) { if (lg[e] > v0) { v0 = lg[e]; i0 = e; } }
    int i1 = -1; float v1 = -1e30f;
    #pragma unroll
    for (int e = 0; e < E_; ++e) {
      if (e == i0) continue;
      if (lg[e] > v1) { v1 = lg[e]; i1 = e; }
    }
    float m  = fmaxf(v0, v1);
    float x0 = expf(v0 - m), x1 = expf(v1 - m);
    float s  = x0 + x1;
    eidx[b] = i0; eidx[B_ + b] = i1;
    gval[b] = x0 / s; gval[B_ + b] = x1 / s;
  }
}

// ---------------- Kernel 3: fused combine + batched GEMM ------------------
// R6: wc intermediate ELIMINATED (75 MB round-trip + one dispatch). B-tiles
// are built per K-step from weight[e0],weight[e1] (f32, L3-resident):
// 8x dwordx4 load -> g0/g1 combine -> v_cvt_pk_bf16_f32 -> ds_write_b128 to
// the SAME swizzled LDS bytes the old DMA wrote, so fragment reads are
// unchanged. A keeps counted-vmcnt DMA (VM2 is order-robust: <=2 outstanding
// guarantees prev A-tile retired). Aux loss computed here from eidx/gval.
__global__ __launch_bounds__(256, 3) void k_moe_gemm(
    const unsigned short* __restrict__ xb, const float* __restrict__ weight,
    const int* __restrict__ eidx, const float* __restrict__ gval,
    const float* __restrict__ bias, float* __restrict__ y,
    float* __restrict__ loss_out) {
  __shared__ unsigned short Alds[2][128 * BK];  // 2 x 8 KB
  __shared__ unsigned short Blds[2][128 * BK];  // 2 x 8 KB

  int flat = blockIdx.x;          // 0..767
  int xcd  = flat & 7;
  int slot = flat >> 3;           // 0..95
  int b    = xcd + 8 * (slot / 24);
  int tile = slot % 24;
  int st = tile & 3;              // S tile 0..3
  int ot = tile >> 2;             // O tile 0..5
  int s0 = st * 128, o0 = ot * 128;

  int tid  = threadIdx.x;
  int wave = tid >> 6, lane = tid & 63;
  int wm = wave & 1, wn = wave >> 1;

  const unsigned short* Abase = xb + ((size_t)(b * S_ + s0)) * D_;

  // ---- aux loss (one thread on the whole chip) ----
  if (flat == 0 && tid == 0) {
    float imp[E_], ldv[E_];
    #pragma unroll
    for (int e = 0; e < E_; ++e) { imp[e] = 0.f; ldv[e] = 0.f; }
    for (int bb = 0; bb < 2 * B_; ++bb) {
      imp[eidx[bb]] += gval[bb];
      ldv[eidx[bb]] += 1.f;
    }
    double mi = 0, ml = 0;
    #pragma unroll
    for (int e = 0; e < E_; ++e) { mi += imp[e]; ml += ldv[e]; }
    mi /= E_; ml /= E_;
    double vi = 0, vl = 0;
    #pragma unroll
    for (int e = 0; e < E_; ++e) {
      double di = imp[e] - mi, dl = ldv[e] - ml;
      vi += di * di; vl += dl * dl;
    }
    vi /= (E_ - 1); vl /= (E_ - 1);
    loss_out[0] = (float)((vi / (mi * mi + 1e-10) + vl / (ml * ml + 1e-10)) * 0.01);
  }

  // ---- pre-load epilogue/gating globals, then drain vmcnt to 0 so the
  // loop's vmcnt counting sees only staging VMEM ----
  int   e0 = eidx[b], e1 = eidx[B_ + b];
  float g0 = gval[b], g1 = gval[B_ + b];
  int col   = lane & 15;
  int rquad = (lane >> 4) * 4;
  float cbv[4];
  #pragma unroll
  for (int ni = 0; ni < 4; ++ni) {
    int n = wn * 64 + ni * 16 + col;
    cbv[ni] = g0 * bias[e0 * O_ + o0 + n] + g1 * bias[e1 * O_ + o0 + n];
  }
  asm volatile("s_waitcnt vmcnt(0)" ::: "memory");

  const float* W0 = weight + (size_t)e0 * WSLICE;
  const float* W1 = weight + (size_t)e1 * WSLICE;

  f32x4 acc[4][4];
  #pragma unroll
  for (int i = 0; i < 4; ++i)
    #pragma unroll
    for (int j = 0; j < 4; ++j) acc[i][j] = (f32x4){0.f, 0.f, 0.f, 0.f};

  int a_chunk0 = wave * 2;
  int a_r = lane >> 2;                              // row within 16-row chunk
  int a_c = (((lane & 3) ^ ((a_r >> 1) & 3))) * 8;  // swizzled source column

  // fragment-read addressing
  int sseg  = lane >> 4;
  int r16   = lane & 15;
  int kphys = (sseg ^ ((r16 >> 1) & 3)) * 8;

  // stage tile at K-offset kk into buf:
  //   1) 8x B-vloads (f32 experts) -> regs        [vmcnt]
  //   2) 2x A-DMAs (global_load_lds)              [vmcnt]
  //   3) VM2: <=2 outstanding -> prev A-tile + these vloads retired;
  //      (ideally leaves this tile's A-DMAs in flight)
  //   4) combine -> cvt_pk -> ds_write_b128 (same swizzled bytes as old DMA)
  auto stage = [&](int buf, int kk) {
    float4 w[8];
    #pragma unroll
    for (int j = 0; j < 2; ++j) {
      int row = o0 + (a_chunk0 + j) * 16 + a_r;
      const float* p0 = W0 + (size_t)row * D_ + kk + a_c;
      const float* p1 = W1 + (size_t)row * D_ + kk + a_c;
      w[j * 4 + 0] = *(const float4*)(p0);
      w[j * 4 + 1] = *(const float4*)(p0 + 4);
      w[j * 4 + 2] = *(const float4*)(p1);
      w[j * 4 + 3] = *(const float4*)(p1 + 4);
    }
    #pragma unroll
    for (int j = 0; j < 2; ++j) {
      int chunk = a_chunk0 + j;
      const unsigned short* srcA =
          Abase + (size_t)(chunk * 16 + a_r) * D_ + kk + a_c;
      async_load16(srcA, &Alds[buf][chunk * 512]);
    }
    asm volatile("s_waitcnt vmcnt(2)" ::: "memory");
    #pragma unroll
    for (int j = 0; j < 2; ++j) {
      int chunk = a_chunk0 + j;
      float4 a0 = w[j * 4 + 0], a1 = w[j * 4 + 1];
      float4 b0 = w[j * 4 + 2], b1 = w[j * 4 + 3];
      uint32_t pk[4];
      pk[0] = cvt_pk_bf16(g0 * a0.x + g1 * b0.x, g0 * a0.y + g1 * b0.y);
      pk[1] = cvt_pk_bf16(g0 * a0.z + g1 * b0.z, g0 * a0.w + g1 * b0.w);
      pk[2] = cvt_pk_bf16(g0 * a1.x + g1 * b1.x, g0 * a1.y + g1 * b1.y);
      pk[3] = cvt_pk_bf16(g0 * a1.z + g1 * b1.z, g0 * a1.w + g1 * b1.w);
      // same bytes the old wc-DMA wrote: chunk*1024 + lane*16
      *(uint4*)((char*)&Blds[buf][chunk * 512] + lane * 16) =
          make_uint4(pk[0], pk[1], pk[2], pk[3]);
    }
  };

  auto compute = [&](int buf) {
    bf16x8 af[4], bfr[4];
    #pragma unroll
    for (int mi = 0; mi < 4; ++mi)
      af[mi] = *(const bf16x8*)(&Alds[buf][(wm * 64 + mi * 16 + r16) * BK + kphys]);
    #pragma unroll
    for (int ni = 0; ni < 4; ++ni)
      bfr[ni] = *(const bf16x8*)(&Blds[buf][(wn * 64 + ni * 16 + r16) * BK + kphys]);
    #pragma unroll
    for (int mi = 0; mi < 4; ++mi)
      #pragma unroll
      for (int ni = 0; ni < 4; ++ni)
        acc[mi][ni] = __builtin_amdgcn_mfma_f32_16x16x32_bf16(
            af[mi], bfr[ni], acc[mi][ni], 0, 0, 0);
  };

  // LGKB: make this wave's ds_writes visible, then rendezvous. The asm
  // memory clobbers also pin compiler-generated LDS/VMEM ops on the correct
  // side of each barrier.
  #define LGKB  do { asm volatile("s_waitcnt lgkmcnt(0)" ::: "memory"); \
                     __builtin_amdgcn_s_barrier(); } while (0)
  #define FENB  do { asm volatile("" ::: "memory"); \
                     __builtin_amdgcn_s_barrier(); } while (0)

  // prologue: tile 0 into buf0 (leaves A_0 in flight; B_0 written)
  stage(0, 0);

  // steady state: 11 pairs. Invariant entering each stage: outstanding
  // vmem = prev tile's 2 A-DMAs.
  #pragma unroll 1
  for (int tt = 0; tt < 11; ++tt) {
    stage(1, (2 * tt + 1) * BK);
    LGKB;              // A_{2tt} retired by stage's VM2; B visible; rendezvous
    compute(0);        // tile 2*tt
    FENB;              // readers done before buf0 is restaged
    stage(0, (2 * tt + 2) * BK);
    LGKB;
    compute(1);        // tile 2*tt+1
    FENB;
  }
  // tiles 22 (buf0, staged at tt=10) and 23
  stage(1, 23 * BK);
  LGKB;
  compute(0);          // tile 22
  asm volatile("s_waitcnt vmcnt(0)" ::: "memory");  // A_23 landed
  __builtin_amdgcn_s_barrier();
  compute(1);          // tile 23

  #undef LGKB
  #undef FENB

  // --- epilogue: y = acc + cbv ---
  float* Y = y + ((size_t)(b * S_ + s0)) * O_ + o0;
  #pragma unroll
  for (int ni = 0; ni < 4; ++ni) {
    int n = wn * 64 + ni * 16 + col;
    #pragma unroll
    for (int mi = 0; mi < 4; ++mi) {
      #pragma unroll
      for (int r = 0; r < 4; ++r) {
        int m = wm * 64 + mi * 16 + rquad + r;
        Y[(size_t)m * O_ + n] = acc[mi][ni][r] + cbv[ni];
      }
    }
  }
}

// ---------------- launcher ----------------
// ws layout (bytes):
//   [0,        1572864)  psum   float[32*16*768]
//   [1573888,  1574144)  eidx   int[64]
//   [1574144,  1574400)  gval   float[64]
//   [2097152, 27262976)  x_bf16 ushort[32*512*768]   (25.2 MB)
extern "C" void kernel_launch(void* const* d_in, const int* in_sizes, int n_in,
                              void* d_out, int out_size, void* d_ws, size_t ws_size,
                              hipStream_t stream) {
  const float* x      = (const float*)d_in[0];
  const float* w_gate = (const float*)d_in[1];
  const float* weight = (const float*)d_in[2];
  const float* bias   = (const float*)d_in[3];
  float* y = (float*)d_out;

  float* psum  = (float*)d_ws;
  int*   eidx  = (int*)((char*)d_ws + 1573888);
  float* gval  = (float*)((char*)d_ws + 1574144);
  unsigned short* xb = (unsigned short*)((char*)d_ws + 2097152);

  k_pool_convert<<<dim3(32, 16), 192, 0, stream>>>(x, xb, psum);
  k_logits<<<32, 256, 0, stream>>>(psum, w_gate, eidx, gval);
  k_moe_gemm<<<768, 256, 0, stream>>>(xb, weight, eidx, gval, bias, y,
                                      y + YSIZE);
}

// Round 10
// 167.741 us; speedup vs baseline: 1.0410x; 1.0410x over previous
//
#include <hip/hip_runtime.h>
#include <hip/hip_bf16.h>
#include <stdint.h>

#define B_ 32
#define S_ 512
#define D_ 768
#define O_ 768
#define E_ 8
#define YSIZE (B_ * S_ * O_)   // 12582912
#define BK 32
#define WSLICE (O_ * D_)       // 589824 elements per expert / per-b slice

typedef __attribute__((ext_vector_type(8))) short bf16x8;
typedef __attribute__((ext_vector_type(4))) float f32x4;

static __device__ __forceinline__ unsigned short f2bf(float f) {
  union { float f; uint32_t u; } v; v.f = f;
  uint32_t u = v.u;
  uint32_t r = u + 0x7fff + ((u >> 16) & 1);   // RNE
  return (unsigned short)(r >> 16);
}

static __device__ __forceinline__ void async_load16(const void* g, void* l) {
  __builtin_amdgcn_global_load_lds(
      (const __attribute__((address_space(1))) void*)g,
      (__attribute__((address_space(3))) void*)l, 16, 0, 0);
}

// ---------------- Kernel 1: pool partial sums + x -> bf16 ----------------
__global__ __launch_bounds__(192) void k_pool_convert(
    const float* __restrict__ x, unsigned short* __restrict__ xb,
    float* __restrict__ psum) {
  int t  = threadIdx.x;          // 0..191
  int b  = blockIdx.x;
  int sc = blockIdx.y;           // 0..15, 32 s-rows each
  size_t rowbase = (size_t)(b * S_ + sc * 32) * D_;
  const float* xp = x + rowbase + 4 * t;
  unsigned short* op = xb + rowbase + 4 * t;
  float4 sum = {0.f, 0.f, 0.f, 0.f};
  #pragma unroll 8
  for (int s = 0; s < 32; ++s) {
    float4 v = *(const float4*)(xp + (size_t)s * D_);
    sum.x += v.x; sum.y += v.y; sum.z += v.z; sum.w += v.w;
    ushort4 o;
    o.x = f2bf(v.x); o.y = f2bf(v.y); o.z = f2bf(v.z); o.w = f2bf(v.w);
    *(ushort4*)(op + (size_t)s * D_) = o;
  }
  *(float4*)(psum + (size_t)(b * 16 + sc) * D_ + 4 * t) = sum;
}

// ---------------- Kernel 2: logits + top-2 + softmax (one block per b) ----
__global__ __launch_bounds__(256) void k_logits(
    const float* __restrict__ psum, const float* __restrict__ w_gate,
    float* __restrict__ gates, int* __restrict__ eidx,
    float* __restrict__ gval) {
  int b = blockIdx.x;
  int tid = threadIdx.x;
  float acc[E_];
  #pragma unroll
  for (int e = 0; e < E_; ++e) acc[e] = 0.f;

  for (int d = tid; d < D_; d += 256) {
    float p = 0.f;
    #pragma unroll
    for (int c = 0; c < 16; ++c) p += psum[(size_t)(b * 16 + c) * D_ + d];
    p *= (1.0f / (float)S_);
    const float* wg = w_gate + d * E_;
    #pragma unroll
    for (int e = 0; e < E_; ++e) acc[e] += p * wg[e];
  }
  #pragma unroll
  for (int off = 32; off > 0; off >>= 1) {
    #pragma unroll
    for (int e = 0; e < E_; ++e) acc[e] += __shfl_down(acc[e], off, 64);
  }
  __shared__ float part[4][E_];
  if ((tid & 63) == 0) {
    #pragma unroll
    for (int e = 0; e < E_; ++e) part[tid >> 6][e] = acc[e];
  }
  __syncthreads();
  if (tid == 0) {
    float lg[E_];
    #pragma unroll
    for (int e = 0; e < E_; ++e)
      lg[e] = part[0][e] + part[1][e] + part[2][e] + part[3][e];
    int i0 = 0; float v0 = lg[0];
    #pragma unroll
    for (int e = 1; e < E_; ++e) { if (lg[e] > v0) { v0 = lg[e]; i0 = e; } }
    int i1 = -1; float v1 = -1e30f;
    #pragma unroll
    for (int e = 0; e < E_; ++e) {
      if (e == i0) continue;
      if (lg[e] > v1) { v1 = lg[e]; i1 = e; }
    }
    float m  = fmaxf(v0, v1);
    float x0 = expf(v0 - m), x1 = expf(v1 - m);
    float s  = x0 + x1;
    float g0 = x0 / s, g1 = x1 / s;
    #pragma unroll
    for (int e = 0; e < E_; ++e)
      gates[b * E_ + e] = (e == i0) ? g0 : ((e == i1) ? g1 : 0.f);
    eidx[b] = i0; eidx[B_ + b] = i1;
    gval[b] = g0; gval[B_ + b] = g1;
  }
}

// ---------------- Kernel 2c: combined weights + fused aux loss ------------
// (R5 verified shape — weight is L3-resident; kernel is write-bound.)
__global__ __launch_bounds__(256) void k_combine(
    const float* __restrict__ weight, const float* __restrict__ gates,
    unsigned short* __restrict__ wc, float* __restrict__ loss_out) {
  __shared__ float gsh[B_][E_];
  int tid = threadIdx.x;
  if (tid < B_ * E_) ((float*)gsh)[tid] = gates[tid];
  __syncthreads();

  if (blockIdx.x == 0 && tid == 0) {
    double mi = 0, ml = 0;
    float imp[E_], ldv[E_];
    #pragma unroll
    for (int e = 0; e < E_; ++e) {
      float s = 0.f, c = 0.f;
      for (int b = 0; b < B_; ++b) {
        float g = gsh[b][e];
        s += g; c += (g > 0.f) ? 1.f : 0.f;
      }
      imp[e] = s; ldv[e] = c;
      mi += s; ml += c;
    }
    mi /= E_; ml /= E_;
    double vi = 0, vl = 0;
    #pragma unroll
    for (int e = 0; e < E_; ++e) {
      double di = imp[e] - mi, dl = ldv[e] - ml;
      vi += di * di; vl += dl * dl;
    }
    vi /= (E_ - 1); vl /= (E_ - 1);
    loss_out[0] = (float)((vi / (mi * mi + 1e-10) + vl / (ml * ml + 1e-10)) * 0.01);
  }

  size_t i = (size_t)blockIdx.x * 1024 + (size_t)tid * 4;
  float v[E_][4];
  #pragma unroll
  for (int e = 0; e < E_; ++e) {
    float4 u = *(const float4*)(weight + (size_t)e * WSLICE + i);
    v[e][0] = u.x; v[e][1] = u.y; v[e][2] = u.z; v[e][3] = u.w;
  }
  #pragma unroll 4
  for (int b = 0; b < B_; ++b) {
    float c[4];
    #pragma unroll
    for (int j = 0; j < 4; ++j) c[j] = 0.f;
    #pragma unroll
    for (int e = 0; e < E_; ++e) {
      float g = gsh[b][e];
      #pragma unroll
      for (int j = 0; j < 4; ++j) c[j] += g * v[e][j];
    }
    uint32_t p0 = (uint32_t)f2bf(c[0]) | ((uint32_t)f2bf(c[1]) << 16);
    uint32_t p1 = (uint32_t)f2bf(c[2]) | ((uint32_t)f2bf(c[3]) << 16);
    *(uint2*)(wc + (size_t)b * WSLICE + i) = make_uint2(p0, p1);
  }
}

// ---------------- Kernel 3: batched GEMM y[b] = x[b] @ Wc[b]^T + bias ------
// R8: REVERT the R6/R7 fusion (regressed 160.7 -> 174.6: weight reads
// replicated 4x at L3 level + f32 vload latency serialized in stage).
// Back to R5's DMA staging + counted vmcnt; SINGLE DELTA vs R5: tile
// 128x128 -> 128x64, grid 768 -> 1536 (3 -> ~5-6 blocks/CU). R7 counters
// showed the gemm latency-bound with a GRID-capped 37.5% occupancy ceiling
// (both pipes ~11%); more resident blocks is the indicated fix.
// Per K-step per thread: 3 DMAs (2 A-chunks + 1 B-chunk); VM3 retires
// exactly the previous tile's 3. LDS 24 KB/block.
__global__ __launch_bounds__(256, 5) void k_moe_gemm(
    const unsigned short* __restrict__ xb, const unsigned short* __restrict__ wc,
    const int* __restrict__ eidx, const float* __restrict__ gval,
    const float* __restrict__ bias, float* __restrict__ y) {
  __shared__ unsigned short Alds[2][128 * BK];  // 2 x 8 KB
  __shared__ unsigned short Blds[2][64 * BK];   // 2 x 4 KB

  int flat = blockIdx.x;          // 0..1535
  int xcd  = flat & 7;
  int slot = flat >> 3;           // 0..191
  int b    = xcd + 8 * (slot / 48);
  int tile = slot % 48;
  int st = tile & 3;              // S tile 0..3   (128 rows)
  int ot = tile >> 2;             // O tile 0..11  (64 cols)
  int s0 = st * 128, o0 = ot * 64;

  int tid  = threadIdx.x;
  int wave = tid >> 6, lane = tid & 63;
  int wm = wave & 1, wn = wave >> 1;   // each wave owns 64 rows x 32 cols

  const unsigned short* Abase = xb + ((size_t)(b * S_ + s0)) * D_;
  const unsigned short* Bbase = wc + (size_t)b * WSLICE + (size_t)o0 * D_;

  // ---- pre-load epilogue globals, drain vmcnt to 0 so loop counting is
  // exact (only staging DMAs in the loop) ----
  int   e0 = eidx[b], e1 = eidx[B_ + b];
  float g0 = gval[b], g1 = gval[B_ + b];
  int col   = lane & 15;
  int rquad = (lane >> 4) * 4;
  float cbv[2];
  #pragma unroll
  for (int ni = 0; ni < 2; ++ni) {
    int n = wn * 32 + ni * 16 + col;
    cbv[ni] = g0 * bias[e0 * O_ + o0 + n] + g1 * bias[e1 * O_ + o0 + n];
  }
  asm volatile("s_waitcnt vmcnt(0)" ::: "memory");

  f32x4 acc[4][2];
  #pragma unroll
  for (int i = 0; i < 4; ++i)
    #pragma unroll
    for (int j = 0; j < 2; ++j) acc[i][j] = (f32x4){0.f, 0.f, 0.f, 0.f};

  int a_chunk0 = wave * 2;                          // A chunks 0..7, 2/wave
  int a_r = lane >> 2;                              // row within 16-row chunk
  int a_c = (((lane & 3) ^ ((a_r >> 1) & 3))) * 8;  // swizzled source column

  // fragment-read addressing (16B-segment XOR swizzle, unchanged)
  int sseg  = lane >> 4;
  int r16   = lane & 15;
  int kphys = (sseg ^ ((r16 >> 1) & 3)) * 8;

  auto stage = [&](int buf, int kk) {   // exactly 3 DMAs per thread
    #pragma unroll
    for (int j = 0; j < 2; ++j) {
      int chunk = a_chunk0 + j;
      const unsigned short* srcA =
          Abase + (size_t)(chunk * 16 + a_r) * D_ + kk + a_c;
      async_load16(srcA, &Alds[buf][chunk * 512]);
    }
    // B: 4 chunks of 16 rows, one per wave
    const unsigned short* srcB =
        Bbase + (size_t)(wave * 16 + a_r) * D_ + kk + a_c;
    async_load16(srcB, &Blds[buf][wave * 512]);
  };

  auto compute = [&](int buf) {
    bf16x8 af[4], bfr[2];
    #pragma unroll
    for (int mi = 0; mi < 4; ++mi)
      af[mi] = *(const bf16x8*)(&Alds[buf][(wm * 64 + mi * 16 + r16) * BK + kphys]);
    #pragma unroll
    for (int ni = 0; ni < 2; ++ni)
      bfr[ni] = *(const bf16x8*)(&Blds[buf][(wn * 32 + ni * 16 + r16) * BK + kphys]);
    #pragma unroll
    for (int mi = 0; mi < 4; ++mi)
      #pragma unroll
      for (int ni = 0; ni < 2; ++ni)
        acc[mi][ni] = __builtin_amdgcn_mfma_f32_16x16x32_bf16(
            af[mi], bfr[ni], acc[mi][ni], 0, 0, 0);
  };

  #define VM3 asm volatile("s_waitcnt vmcnt(3)" ::: "memory")
  #define VM0 asm volatile("s_waitcnt vmcnt(0)" ::: "memory")
  #define BARx __builtin_amdgcn_s_barrier()

  // prologue: tile 0 into buf0 (3 DMAs in flight)
  stage(0, 0);

  // steady state: tiles 0..21 in pairs. Invariant at each VM3: outstanding
  // = 6 (prev tile's 3 + next tile's 3); waiting to 3 retires exactly the
  // tile about to be computed (vmcnt retires in issue order).
  #pragma unroll 1
  for (int tt = 0; tt < 11; ++tt) {
    stage(1, (2 * tt + 1) * BK);
    VM3; BARx;
    compute(0);                  // tile 2*tt
    BARx;                        // readers done before buf0 restage
    stage(0, (2 * tt + 2) * BK);
    VM3; BARx;
    compute(1);                  // tile 2*tt+1
    BARx;
  }
  // tiles 22 (buf0, staged at tt=10) and 23
  stage(1, 23 * BK);
  VM3; BARx;
  compute(0);                    // tile 22
  VM0; BARx;                     // drain tile 23's DMAs
  compute(1);                    // tile 23

  #undef VM3
  #undef VM0
  #undef BARx

  // --- epilogue: y = acc + cbv (bias pre-combined) ---
  float* Y = y + ((size_t)(b * S_ + s0)) * O_ + o0;
  #pragma unroll
  for (int ni = 0; ni < 2; ++ni) {
    int n = wn * 32 + ni * 16 + col;
    #pragma unroll
    for (int mi = 0; mi < 4; ++mi) {
      #pragma unroll
      for (int r = 0; r < 4; ++r) {
        int m = wm * 64 + mi * 16 + rquad + r;
        Y[(size_t)m * O_ + n] = acc[mi][ni][r] + cbv[ni];
      }
    }
  }
}

// ---------------- launcher ----------------
// ws layout (bytes):
//   [0,        1572864)  psum   float[32*16*768]
//   [1572864,  1573888)  gates  float[32*8]
//   [1573888,  1574144)  eidx   int[64]
//   [1574144,  1574400)  gval   float[64]
//   [2097152, 27262976)  x_bf16 ushort[32*512*768]   (25.2 MB)
//   [27262976,65011712)  wc     ushort[32*768*768]   (37.7 MB)
extern "C" void kernel_launch(void* const* d_in, const int* in_sizes, int n_in,
                              void* d_out, int out_size, void* d_ws, size_t ws_size,
                              hipStream_t stream) {
  const float* x      = (const float*)d_in[0];
  const float* w_gate = (const float*)d_in[1];
  const float* weight = (const float*)d_in[2];
  const float* bias   = (const float*)d_in[3];
  float* y = (float*)d_out;

  float* psum  = (float*)d_ws;
  float* gates = (float*)((char*)d_ws + 1572864);
  int*   eidx  = (int*)((char*)d_ws + 1573888);
  float* gval  = (float*)((char*)d_ws + 1574144);
  unsigned short* xb = (unsigned short*)((char*)d_ws + 2097152);
  unsigned short* wc = (unsigned short*)((char*)d_ws + 27262976);

  k_pool_convert<<<dim3(32, 16), 192, 0, stream>>>(x, xb, psum);
  k_logits<<<32, 256, 0, stream>>>(psum, w_gate, gates, eidx, gval);
  k_combine<<<576, 256, 0, stream>>>(weight, gates, wc, y + YSIZE);
  k_moe_gemm<<<1536, 256, 0, stream>>>(xb, wc, eidx, gval, bias, y);
}

// Round 11
// 161.829 us; speedup vs baseline: 1.0790x; 1.0365x over previous
//
#include <hip/hip_runtime.h>
#include <hip/hip_bf16.h>
#include <stdint.h>

#define B_ 32
#define S_ 512
#define D_ 768
#define O_ 768
#define E_ 8
#define YSIZE (B_ * S_ * O_)   // 12582912
#define BK 32
#define WSLICE (O_ * D_)       // 589824 elements per expert / per-b slice

typedef __attribute__((ext_vector_type(8))) short bf16x8;
typedef __attribute__((ext_vector_type(4))) float f32x4;

static __device__ __forceinline__ unsigned short f2bf(float f) {
  union { float f; uint32_t u; } v; v.f = f;
  uint32_t u = v.u;
  uint32_t r = u + 0x7fff + ((u >> 16) & 1);   // RNE
  return (unsigned short)(r >> 16);
}

static __device__ __forceinline__ void async_load16(const void* g, void* l) {
  __builtin_amdgcn_global_load_lds(
      (const __attribute__((address_space(1))) void*)g,
      (__attribute__((address_space(3))) void*)l, 16, 0, 0);
}

// ---------------- Kernel 1: pool partial sums + x -> bf16 ----------------
__global__ __launch_bounds__(192) void k_pool_convert(
    const float* __restrict__ x, unsigned short* __restrict__ xb,
    float* __restrict__ psum) {
  int t  = threadIdx.x;          // 0..191
  int b  = blockIdx.x;
  int sc = blockIdx.y;           // 0..15, 32 s-rows each
  size_t rowbase = (size_t)(b * S_ + sc * 32) * D_;
  const float* xp = x + rowbase + 4 * t;
  unsigned short* op = xb + rowbase + 4 * t;
  float4 sum = {0.f, 0.f, 0.f, 0.f};
  #pragma unroll 8
  for (int s = 0; s < 32; ++s) {
    float4 v = *(const float4*)(xp + (size_t)s * D_);
    sum.x += v.x; sum.y += v.y; sum.z += v.z; sum.w += v.w;
    ushort4 o;
    o.x = f2bf(v.x); o.y = f2bf(v.y); o.z = f2bf(v.z); o.w = f2bf(v.w);
    *(ushort4*)(op + (size_t)s * D_) = o;
  }
  *(float4*)(psum + (size_t)(b * 16 + sc) * D_ + 4 * t) = sum;
}

// ---------------- Kernel 2: logits + top-2 + softmax (one block per b) ----
__global__ __launch_bounds__(256) void k_logits(
    const float* __restrict__ psum, const float* __restrict__ w_gate,
    float* __restrict__ gates, int* __restrict__ eidx,
    float* __restrict__ gval) {
  int b = blockIdx.x;
  int tid = threadIdx.x;
  float acc[E_];
  #pragma unroll
  for (int e = 0; e < E_; ++e) acc[e] = 0.f;

  for (int d = tid; d < D_; d += 256) {
    float p = 0.f;
    #pragma unroll
    for (int c = 0; c < 16; ++c) p += psum[(size_t)(b * 16 + c) * D_ + d];
    p *= (1.0f / (float)S_);
    const float* wg = w_gate + d * E_;
    #pragma unroll
    for (int e = 0; e < E_; ++e) acc[e] += p * wg[e];
  }
  #pragma unroll
  for (int off = 32; off > 0; off >>= 1) {
    #pragma unroll
    for (int e = 0; e < E_; ++e) acc[e] += __shfl_down(acc[e], off, 64);
  }
  __shared__ float part[4][E_];
  if ((tid & 63) == 0) {
    #pragma unroll
    for (int e = 0; e < E_; ++e) part[tid >> 6][e] = acc[e];
  }
  __syncthreads();
  if (tid == 0) {
    float lg[E_];
    #pragma unroll
    for (int e = 0; e < E_; ++e)
      lg[e] = part[0][e] + part[1][e] + part[2][e] + part[3][e];
    int i0 = 0; float v0 = lg[0];
    #pragma unroll
    for (int e = 1; e < E_; ++e) { if (lg[e] > v0) { v0 = lg[e]; i0 = e; } }
    int i1 = -1; float v1 = -1e30f;
    #pragma unroll
    for (int e = 0; e < E_; ++e) {
      if (e == i0) continue;
      if (lg[e] > v1) { v1 = lg[e]; i1 = e; }
    }
    float m  = fmaxf(v0, v1);
    float x0 = expf(v0 - m), x1 = expf(v1 - m);
    float s  = x0 + x1;
    float g0 = x0 / s, g1 = x1 / s;
    #pragma unroll
    for (int e = 0; e < E_; ++e)
      gates[b * E_ + e] = (e == i0) ? g0 : ((e == i1) ? g1 : 0.f);
    eidx[b] = i0; eidx[B_ + b] = i1;
    gval[b] = g0; gval[B_ + b] = g1;
  }
}

// ---------------- Kernel 2c: combined weights + fused aux loss ------------
// (R5 verified shape — weight is L3-resident; kernel is write-bound.)
__global__ __launch_bounds__(256) void k_combine(
    const float* __restrict__ weight, const float* __restrict__ gates,
    unsigned short* __restrict__ wc, float* __restrict__ loss_out) {
  __shared__ float gsh[B_][E_];
  int tid = threadIdx.x;
  if (tid < B_ * E_) ((float*)gsh)[tid] = gates[tid];
  __syncthreads();

  if (blockIdx.x == 0 && tid == 0) {
    double mi = 0, ml = 0;
    float imp[E_], ldv[E_];
    #pragma unroll
    for (int e = 0; e < E_; ++e) {
      float s = 0.f, c = 0.f;
      for (int b = 0; b < B_; ++b) {
        float g = gsh[b][e];
        s += g; c += (g > 0.f) ? 1.f : 0.f;
      }
      imp[e] = s; ldv[e] = c;
      mi += s; ml += c;
    }
    mi /= E_; ml /= E_;
    double vi = 0, vl = 0;
    #pragma unroll
    for (int e = 0; e < E_; ++e) {
      double di = imp[e] - mi, dl = ldv[e] - ml;
      vi += di * di; vl += dl * dl;
    }
    vi /= (E_ - 1); vl /= (E_ - 1);
    loss_out[0] = (float)((vi / (mi * mi + 1e-10) + vl / (ml * ml + 1e-10)) * 0.01);
  }

  size_t i = (size_t)blockIdx.x * 1024 + (size_t)tid * 4;
  float v[E_][4];
  #pragma unroll
  for (int e = 0; e < E_; ++e) {
    float4 u = *(const float4*)(weight + (size_t)e * WSLICE + i);
    v[e][0] = u.x; v[e][1] = u.y; v[e][2] = u.z; v[e][3] = u.w;
  }
  #pragma unroll 4
  for (int b = 0; b < B_; ++b) {
    float c[4];
    #pragma unroll
    for (int j = 0; j < 4; ++j) c[j] = 0.f;
    #pragma unroll
    for (int e = 0; e < E_; ++e) {
      float g = gsh[b][e];
      #pragma unroll
      for (int j = 0; j < 4; ++j) c[j] += g * v[e][j];
    }
    uint32_t p0 = (uint32_t)f2bf(c[0]) | ((uint32_t)f2bf(c[1]) << 16);
    uint32_t p1 = (uint32_t)f2bf(c[2]) | ((uint32_t)f2bf(c[3]) << 16);
    *(uint2*)(wc + (size_t)b * WSLICE + i) = make_uint2(p0, p1);
  }
}

// ---------------- Kernel 3: batched GEMM y[b] = x[b] @ Wc[b]^T + bias ------
// R10: REVERT R8's 128x64 split (regressed: 2x A-replication, half the MFMA
// per barrier; occupancy was NOT binding). Base = R5's 128x128/768-block
// structure; SINGLE DELTA: pipeline depth 2 -> 3. Triple-buffered LDS
// (3 x 16 KB = 48 KB, same 3 blocks/CU LDS cap), stage tile t+2 before
// computing tile t, vmcnt(8) retires exactly tile t's 4 DMAs while tiles
// t+1/t+2 (8 DMAs) stay in flight. Each tile's loads now get TWO compute
// phases (~500 cyc) of slack vs the measured ~200-900 cyc L2/HBM latency —
// R5/R8's 2-deep gave only one short phase, so every counted wait stalled
// (m218: the win is loads spanning phases, not the counted wait itself).
__global__ __launch_bounds__(256, 3) void k_moe_gemm(
    const unsigned short* __restrict__ xb, const unsigned short* __restrict__ wc,
    const int* __restrict__ eidx, const float* __restrict__ gval,
    const float* __restrict__ bias, float* __restrict__ y) {
  __shared__ unsigned short Alds[3][128 * BK];  // 3 x 8 KB
  __shared__ unsigned short Blds[3][128 * BK];  // 3 x 8 KB

  int flat = blockIdx.x;          // 0..767
  int xcd  = flat & 7;
  int slot = flat >> 3;           // 0..95
  int b    = xcd + 8 * (slot / 24);
  int tile = slot % 24;
  int st = tile & 3;              // S tile 0..3
  int ot = tile >> 2;             // O tile 0..5
  int s0 = st * 128, o0 = ot * 128;

  int tid  = threadIdx.x;
  int wave = tid >> 6, lane = tid & 63;
  int wm = wave & 1, wn = wave >> 1;

  const unsigned short* Abase = xb + ((size_t)(b * S_ + s0)) * D_;
  const unsigned short* Bbase = wc + (size_t)b * WSLICE + (size_t)o0 * D_;

  // ---- pre-load epilogue globals, drain vmcnt to 0 so loop counting is
  // exact (only staging DMAs in the loop) ----
  int   e0 = eidx[b], e1 = eidx[B_ + b];
  float g0 = gval[b], g1 = gval[B_ + b];
  int col   = lane & 15;
  int rquad = (lane >> 4) * 4;
  float cbv[4];
  #pragma unroll
  for (int ni = 0; ni < 4; ++ni) {
    int n = wn * 64 + ni * 16 + col;
    cbv[ni] = g0 * bias[e0 * O_ + o0 + n] + g1 * bias[e1 * O_ + o0 + n];
  }
  asm volatile("s_waitcnt vmcnt(0)" ::: "memory");

  f32x4 acc[4][4];
  #pragma unroll
  for (int i = 0; i < 4; ++i)
    #pragma unroll
    for (int j = 0; j < 4; ++j) acc[i][j] = (f32x4){0.f, 0.f, 0.f, 0.f};

  int a_chunk0 = wave * 2;
  int a_r = lane >> 2;                              // row within 16-row chunk
  int a_c = (((lane & 3) ^ ((a_r >> 1) & 3))) * 8;  // swizzled source column

  // fragment-read addressing (16B-segment XOR swizzle, unchanged)
  int sseg  = lane >> 4;
  int r16   = lane & 15;
  int kphys = (sseg ^ ((r16 >> 1) & 3)) * 8;

  auto stage = [&](int buf, int kk) {   // exactly 4 DMAs per thread
    #pragma unroll
    for (int j = 0; j < 2; ++j) {
      int chunk = a_chunk0 + j;
      const unsigned short* srcA =
          Abase + (size_t)(chunk * 16 + a_r) * D_ + kk + a_c;
      async_load16(srcA, &Alds[buf][chunk * 512]);
      const unsigned short* srcB =
          Bbase + (size_t)(chunk * 16 + a_r) * D_ + kk + a_c;
      async_load16(srcB, &Blds[buf][chunk * 512]);
    }
  };

  auto compute = [&](int buf) {
    bf16x8 af[4], bfr[4];
    #pragma unroll
    for (int mi = 0; mi < 4; ++mi)
      af[mi] = *(const bf16x8*)(&Alds[buf][(wm * 64 + mi * 16 + r16) * BK + kphys]);
    #pragma unroll
    for (int ni = 0; ni < 4; ++ni)
      bfr[ni] = *(const bf16x8*)(&Blds[buf][(wn * 64 + ni * 16 + r16) * BK + kphys]);
    #pragma unroll
    for (int mi = 0; mi < 4; ++mi)
      #pragma unroll
      for (int ni = 0; ni < 4; ++ni)
        acc[mi][ni] = __builtin_amdgcn_mfma_f32_16x16x32_bf16(
            af[mi], bfr[ni], acc[mi][ni], 0, 0, 0);
  };

  #define VM8 asm volatile("s_waitcnt vmcnt(8)" ::: "memory")
  #define VM4 asm volatile("s_waitcnt vmcnt(4)" ::: "memory")
  #define VM0 asm volatile("s_waitcnt vmcnt(0)" ::: "memory")
  #define BARx __builtin_amdgcn_s_barrier()

  // prologue: tiles 0,1 staged (8 DMAs in flight)
  stage(0, 0);
  stage(1, BK);

  // steady state, t = 0..20 in unrolled-by-3 groups (buffer indices are
  // compile-time constants). Iter t: stage(t+2) -> 12 outstanding; VM8
  // retires exactly tile t's 4; barrier; compute(t); barrier.
  // Buffer reuse safety: buf[(t+2)%3]'s previous occupant (tile t-1) was
  // computed in iter t-1 and all readers passed that iter's trailing BARx.
  #pragma unroll 1
  for (int tt = 0; tt < 7; ++tt) {
    int t0 = 3 * tt;
    stage(2, (t0 + 2) * BK);
    VM8; BARx;
    compute(0);                  // tile t0
    BARx;
    stage(0, (t0 + 3) * BK);
    VM8; BARx;
    compute(1);                  // tile t0+1
    BARx;
    stage(1, (t0 + 4) * BK);
    VM8; BARx;
    compute(2);                  // tile t0+2
    BARx;
  }
  // t=21: stage tile 23 (buf 2), compute tile 21 (buf 0)
  stage(2, 23 * BK);
  VM8; BARx;
  compute(0);                    // tile 21
  BARx;
  // t=22: outstanding = tiles 22,23 (8); VM4 retires tile 22's
  VM4; BARx;
  compute(1);                    // tile 22
  // t=23
  VM0; BARx;
  compute(2);                    // tile 23

  #undef VM8
  #undef VM4
  #undef VM0
  #undef BARx

  // --- epilogue: y = acc + cbv (bias pre-combined) ---
  float* Y = y + ((size_t)(b * S_ + s0)) * O_ + o0;
  #pragma unroll
  for (int ni = 0; ni < 4; ++ni) {
    int n = wn * 64 + ni * 16 + col;
    #pragma unroll
    for (int mi = 0; mi < 4; ++mi) {
      #pragma unroll
      for (int r = 0; r < 4; ++r) {
        int m = wm * 64 + mi * 16 + rquad + r;
        Y[(size_t)m * O_ + n] = acc[mi][ni][r] + cbv[ni];
      }
    }
  }
}

// ---------------- launcher ----------------
// ws layout (bytes):
//   [0,        1572864)  psum   float[32*16*768]
//   [1572864,  1573888)  gates  float[32*8]
//   [1573888,  1574144)  eidx   int[64]
//   [1574144,  1574400)  gval   float[64]
//   [2097152, 27262976)  x_bf16 ushort[32*512*768]   (25.2 MB)
//   [27262976,65011712)  wc     ushort[32*768*768]   (37.7 MB)
extern "C" void kernel_launch(void* const* d_in, const int* in_sizes, int n_in,
                              void* d_out, int out_size, void* d_ws, size_t ws_size,
                              hipStream_t stream) {
  const float* x      = (const float*)d_in[0];
  const float* w_gate = (const float*)d_in[1];
  const float* weight = (const float*)d_in[2];
  const float* bias   = (const float*)d_in[3];
  float* y = (float*)d_out;

  float* psum  = (float*)d_ws;
  float* gates = (float*)((char*)d_ws + 1572864);
  int*   eidx  = (int*)((char*)d_ws + 1573888);
  float* gval  = (float*)((char*)d_ws + 1574144);
  unsigned short* xb = (unsigned short*)((char*)d_ws + 2097152);
  unsigned short* wc = (unsigned short*)((char*)d_ws + 27262976);

  k_pool_convert<<<dim3(32, 16), 192, 0, stream>>>(x, xb, psum);
  k_logits<<<32, 256, 0, stream>>>(psum, w_gate, gates, eidx, gval);
  k_combine<<<576, 256, 0, stream>>>(weight, gates, wc, y + YSIZE);
  k_moe_gemm<<<768, 256, 0, stream>>>(xb, wc, eidx, gval, bias, y);
}